// Round 4
// baseline (865.098 us; speedup 1.0000x reference)
//
#include <hip/hip_runtime.h>
#include <hip/hip_bf16.h>

// B=2, N=1024, D=512, H=8, DH=64, HD=512, FF=2048, DEPTH=4.
// Dual-dtype IO (bf16 or fp32, runtime-detected from ln1_g word0).
// bf16 MFMA 16x16x32 everywhere, fp32 accum, fp32 residual chain.
// R4: LN fused into consumer GEMMs (mgemm_ln: A-resident LDS, fp32 in,
//     LN applied in staging; qkv EPI=1, ff1 EPI=3) — ln_kernel gone;
//     cast_in+rcat merged (input_prep); attn_out+cast_out merged (outputs).

using bf16 = __hip_bfloat16;
typedef __attribute__((ext_vector_type(8))) short short8;
typedef __attribute__((ext_vector_type(4))) float float4v;
typedef __attribute__((ext_vector_type(2))) unsigned int uint2v;

__device__ __forceinline__ float ldsel(const void* p, long long i, bool isbf) {
    return isbf ? __bfloat162float(((const bf16*)p)[i]) : ((const float*)p)[i];
}
__device__ __forceinline__ float bf2f(short u) {
    return __uint_as_float(((unsigned)(unsigned short)u) << 16);
}
__device__ __forceinline__ short f2bf(float f) {
    bf16 h = __float2bfloat16(f);
    return *reinterpret_cast<short*>(&h);
}

__global__ void detect_kernel(const unsigned int* __restrict__ g, int* __restrict__ flag) {
    if (threadIdx.x == 0) flag[0] = ((g[0] & 0xFFFFu) != 0u) ? 1 : 0;
}

// y==0: cast x_in -> xbuf (fp32). y==1..3: rcat plane.
__global__ __launch_bounds__(256) void input_prep(
    const void* __restrict__ x_in, const void* __restrict__ r0,
    const void* __restrict__ r1, const void* __restrict__ r2,
    float* __restrict__ xbuf, bf16* __restrict__ rcat,
    const int* __restrict__ flagp) {
    bool bf = flagp[0] != 0;
    int y = blockIdx.y;
    int i = blockIdx.x * 256 + threadIdx.x;          // 0..131071
    if (y == 0) {
        long long b = (long long)i * 8;
        if (bf) {
            short8 v = *(const short8*)((const bf16*)x_in + b);
            float4v o0, o1;
            #pragma unroll
            for (int j = 0; j < 4; ++j) { o0[j] = bf2f(v[j]); o1[j] = bf2f(v[4 + j]); }
            *(float4v*)(xbuf + b) = o0;
            *(float4v*)(xbuf + b + 4) = o1;
        } else {
            float4v a0 = *(const float4v*)((const float*)x_in + b);
            float4v a1 = *(const float4v*)((const float*)x_in + b + 4);
            *(float4v*)(xbuf + b) = a0;
            *(float4v*)(xbuf + b + 4) = a1;
        }
    } else {
        int s = y - 1;
        const void* src = (s == 0) ? r0 : ((s == 1) ? r1 : r2);
        int m = i >> 6, k8 = (i & 63) * 8;
        long long b = (long long)m * 512 + k8;
        short8 v;
        if (bf) {
            v = *(const short8*)((const bf16*)src + b);
        } else {
            float4v a0 = *(const float4v*)((const float*)src + b);
            float4v a1 = *(const float4v*)((const float*)src + b + 4);
            #pragma unroll
            for (int j = 0; j < 4; ++j) { v[j] = f2bf(a0[j]); v[4 + j] = f2bf(a1[j]); }
        }
        *(short8*)(rcat + (size_t)m * 1536 + s * 512 + k8) = v;
    }
}

// blocks [0,512): xbuf -> d_out x-region. blocks [512,8704): attn -> d_out.
__global__ __launch_bounds__(256) void outputs_kernel(
    const float* __restrict__ xbuf, const bf16* __restrict__ attn,
    void* __restrict__ out, const int* __restrict__ flagp) {
    bool bf = flagp[0] != 0;
    int bid = blockIdx.x;
    if (bid < 512) {
        long long b = ((long long)bid * 256 + threadIdx.x) * 8;
        float4v a0 = *(const float4v*)(xbuf + b);
        float4v a1 = *(const float4v*)(xbuf + b + 4);
        if (bf) {
            short8 v;
            #pragma unroll
            for (int j = 0; j < 4; ++j) { v[j] = f2bf(a0[j]); v[4 + j] = f2bf(a1[j]); }
            *(short8*)((bf16*)out + b) = v;
        } else {
            *(float4v*)((float*)out + b) = a0;
            *(float4v*)((float*)out + b + 4) = a1;
        }
    } else {
        long long e = ((long long)(bid - 512) * 256 + threadIdx.x) * 8;  // < 16777216
        short8 v = *(const short8*)(attn + e);
        if (bf) {
            *(short8*)((bf16*)out + 1048576 + e) = v;
        } else {
            float4v o0, o1;
            #pragma unroll
            for (int j = 0; j < 4; ++j) { o0[j] = bf2f(v[j]); o1[j] = bf2f(v[4 + j]); }
            float* op = (float*)out + 1048576 + e;
            *(float4v*)op = o0;
            *(float4v*)(op + 4) = o1;
        }
    }
}

// ---- all weight transposes (all 4 layers) in ONE exact-sized dispatch ----
__global__ __launch_bounds__(256) void prep_weights(
    const void* __restrict__ s0, const void* __restrict__ s1, const void* __restrict__ s2,
    const void* __restrict__ s3, const void* __restrict__ s4, const void* __restrict__ s5,
    const void* __restrict__ s6, bf16* __restrict__ arena,
    const int* __restrict__ flagp) {
    const bool bf = flagp[0] != 0;
    const int bid = blockIdx.x;
    const int l = bid / 960;
    const int rem = bid - l * 960;
    const int LW = 3932160;
    const int L = l * LW;

    int j, tile, tx, ldi, ldo;
    long long ioff;
    int dstoff;
    if (rem < 192)      { j = 0; tile = rem;                tx = 24; ldi = 1536; ldo = 512;
                          ioff = (long long)l * 786432;  dstoff = L; }
    else if (rem < 448) { j = 1 + ((rem - 192) >> 6); tile = (rem - 192) & 63; tx = 8; ldi = 512;
                          ioff = (long long)l * 262144;
                          if (j <= 3) { ldo = 1536; dstoff = L + 786432 + (j - 1) * 512; }
                          else        { ldo = 512;  dstoff = L + 1572864; } }
    else if (rem < 704) { j = 5; tile = rem - 448;          tx = 32; ldi = 2048; ldo = 512;
                          ioff = (long long)l * 1048576; dstoff = L + 1835008; }
    else                { j = 6; tile = rem - 704;          tx = 8;  ldi = 512;  ldo = 2048;
                          ioff = (long long)l * 1048576; dstoff = L + 2883584; }
    const void* in = (j == 0) ? s0 : (j == 1) ? s1 : (j == 2) ? s2 :
                     (j == 3) ? s3 : (j == 4) ? s4 : (j == 5) ? s5 : s6;
    bf16* out = arena + dstoff;
    const int bx = tile % tx, by = tile / tx;
    const int n0 = bx * 64, k0 = by * 64;
    const int tid = threadIdx.x;

    __shared__ bf16 t[64][72];

    if (bf) {
        const bf16* inb = (const bf16*)in + ioff;
        #pragma unroll
        for (int p = 0; p < 2; ++p) {
            int e = tid + p * 256;
            int r = e >> 3, c = (e & 7) * 8;
            *(uint4*)&t[r][c] = *(const uint4*)(inb + (size_t)(k0 + r) * ldi + n0 + c);
        }
    } else {
        const float* inf = (const float*)in + ioff;
        #pragma unroll
        for (int p = 0; p < 4; ++p) {
            int e = tid + p * 256;
            int r = e >> 4, c = (e & 15) * 4;
            float4v v = *(const float4v*)(inf + (size_t)(k0 + r) * ldi + n0 + c);
            union { bf16 h[4]; uint2v u; } w;
            #pragma unroll
            for (int q = 0; q < 4; ++q) w.h[q] = __float2bfloat16(v[q]);
            *reinterpret_cast<uint2v*>(&t[r][c]) = w.u;
        }
    }
    __syncthreads();
    #pragma unroll
    for (int p = 0; p < 2; ++p) {
        int e = tid + p * 256;
        int r = e >> 3, c = (e & 7) * 8;
        union { short8 s; uint4 u; } o;
        #pragma unroll
        for (int q = 0; q < 8; ++q)
            o.s[q] = *reinterpret_cast<const short*>(&t[c + q][r]);
        *(uint4*)(out + (size_t)(n0 + r) * ldo + k0 + c) = o.u;
    }
}

// ---- MFMA GEMM 64x64 tile (4 waves, 32x32 per wave) ----
// EPI: 1 qkv; 2 fp32 +bias+resid; 5 bf16 plain store.
template<int EPI>
__global__ __launch_bounds__(256) void mgemm64(
    const bf16* __restrict__ A, int lda, long long sAb, long long sAh,
    const bf16* __restrict__ B, int ldb, long long sBb, long long sBh,
    void* __restrict__ Cv, int ldc, long long sCb, long long sCh,
    int K,
    const void* __restrict__ bias, long long biasoff,
    float* __restrict__ resid,
    bf16* __restrict__ aux,
    const int* __restrict__ flagp) {
    const bool flg = flagp[0] != 0;
    const int tid = threadIdx.x;
    const int lane = tid & 63, wave = tid >> 6;
    const int m0 = blockIdx.y * 64, n0 = blockIdx.x * 64;
    const int zb = (int)(blockIdx.z >> 3), zh = (int)(blockIdx.z & 7);
    A += (size_t)zb * sAb + (size_t)zh * sAh;
    B += (size_t)zb * sBb + (size_t)zh * sBh;

    __shared__ bf16 As[64][40];
    __shared__ bf16 Bs[64][40];

    const int ar = tid >> 2, ak = (tid & 3) * 8;
    const bf16* Ap = A + (size_t)(m0 + ar) * lda + ak;
    const bf16* Bp = B + (size_t)(n0 + ar) * ldb + ak;

    const int wm = (wave >> 1) * 32, wn = (wave & 1) * 32;
    const int fr = lane & 15, fq = lane >> 4;

    float4v acc[2][2] = {};

    uint4 a0 = *(const uint4*)Ap;
    uint4 b0 = *(const uint4*)Bp;

    for (int k0 = 0; k0 < K; k0 += 32) {
        __syncthreads();
        *(uint4*)&As[ar][ak] = a0;
        *(uint4*)&Bs[ar][ak] = b0;
        if (k0 + 32 < K) {
            a0 = *(const uint4*)(Ap + k0 + 32);
            b0 = *(const uint4*)(Bp + k0 + 32);
        }
        __syncthreads();
        union { uint4 u; short8 s; } ua[2], ub[2];
        #pragma unroll
        for (int i = 0; i < 2; ++i) ua[i].u = *(const uint4*)&As[wm + i * 16 + fr][fq * 8];
        #pragma unroll
        for (int j = 0; j < 2; ++j) ub[j].u = *(const uint4*)&Bs[wn + j * 16 + fr][fq * 8];
        #pragma unroll
        for (int i = 0; i < 2; ++i)
            #pragma unroll
            for (int j = 0; j < 2; ++j)
                acc[i][j] = __builtin_amdgcn_mfma_f32_16x16x32_bf16(ua[i].s, ub[j].s, acc[i][j], 0, 0, 0);
    }

    const long long coff = (long long)zb * sCb + (long long)zh * sCh;
    #pragma unroll
    for (int i = 0; i < 2; ++i) {
        #pragma unroll
        for (int j = 0; j < 2; ++j) {
            #pragma unroll
            for (int r = 0; r < 4; ++r) {
                int m = m0 + wm + i * 16 + fq * 4 + r;
                int n = n0 + wn + j * 16 + fr;
                float v = acc[i][j][r];
                if (EPI == 1) {
                    bf16* C = (bf16*)Cv;
                    if (n < 512) {
                        C[(size_t)m * ldc + n] = __float2bfloat16(v + ldsel(bias, biasoff + n, flg));
                    } else if (n < 1024) {
                        C[(size_t)m * ldc + n] = __float2bfloat16(v);
                    } else {
                        int h = (n >> 6) & 7, d = n & 63, ii = m & 1023, bb = m >> 10;
                        aux[(size_t)(bb * 8 + h) * 65536 + (size_t)d * 1024 + ii] = __float2bfloat16(v);
                    }
                } else if (EPI == 2) {
                    float* C = (float*)Cv;
                    C[(size_t)m * ldc + n] = v + ldsel(bias, biasoff + n, flg) + resid[(size_t)m * ldc + n];
                } else if (EPI == 5) {
                    bf16* C = (bf16*)Cv + coff;
                    C[(size_t)m * ldc + n] = __float2bfloat16(v);
                }
            }
        }
    }
}

// ---- LN-fused GEMM: A = fp32 xbuf rows (lda=512, K=512 fixed); LN applied
// during staging into a RESIDENT As[64][524] bf16 tile; then K-loop with only
// B staged per step. EPI: 1 = qkv epilogue, 3 = gelu(+bias) bf16 store.
template<int EPI>
__global__ __launch_bounds__(256) void mgemm_ln(
    const float* __restrict__ A,
    const void* __restrict__ g, long long goff,
    const void* __restrict__ bta, long long boff,
    const bf16* __restrict__ B, int ldb,
    void* __restrict__ Cv, int ldc,
    const void* __restrict__ bias, long long biasoff,
    bf16* __restrict__ aux,
    const int* __restrict__ flagp) {
    const bool flg = flagp[0] != 0;
    const int tid = threadIdx.x;
    const int lane = tid & 63, wave = tid >> 6;
    const int m0 = blockIdx.y * 64, n0 = blockIdx.x * 64;

    __shared__ bf16 As[64][524];   // row stride 1048B = 262 dw = 6 mod 32 -> conflict-free
    __shared__ bf16 Bs[64][40];
    __shared__ float gs[512], bs[512];

    const int ar = tid >> 2, ak = (tid & 3) * 8;
    const bf16* Bp = B + (size_t)(n0 + ar) * ldb + ak;
    uint4 b0 = *(const uint4*)Bp;

    // stage gamma/beta (fp32) into LDS, coalesced
    gs[tid]       = ldsel(g,   goff + tid, flg);
    gs[tid + 256] = ldsel(g,   goff + tid + 256, flg);
    bs[tid]       = ldsel(bta, boff + tid, flg);
    bs[tid + 256] = ldsel(bta, boff + tid + 256, flg);

    // LN: thread t -> row r=t>>2, quarter qc=t&3 (cols qc*128..+128)
    const int r = tid >> 2, qc = tid & 3;
    const float* xr = A + (size_t)(m0 + r) * 512 + qc * 128;
    float s = 0.f, q = 0.f;
    #pragma unroll
    for (int c = 0; c < 128; c += 4) {
        float4v v = *(const float4v*)(xr + c);
        #pragma unroll
        for (int u = 0; u < 4; ++u) { s += v[u]; q += v[u] * v[u]; }
    }
    s += __shfl_xor(s, 1); q += __shfl_xor(q, 1);
    s += __shfl_xor(s, 2); q += __shfl_xor(q, 2);
    const float mean = s * (1.f / 512.f);
    const float rstd = rsqrtf(q * (1.f / 512.f) - mean * mean + 1e-5f);

    __syncthreads();   // gs/bs visible
    #pragma unroll
    for (int c = 0; c < 128; c += 8) {
        float4v v0 = *(const float4v*)(xr + c);
        float4v v1 = *(const float4v*)(xr + c + 4);
        union { bf16 h[8]; uint4 u; } w;
        #pragma unroll
        for (int u = 0; u < 4; ++u) {
            int cc = qc * 128 + c + u;
            w.h[u]     = __float2bfloat16((v0[u] - mean) * rstd * gs[cc] + bs[cc]);
            w.h[4 + u] = __float2bfloat16((v1[u] - mean) * rstd * gs[cc + 4] + bs[cc + 4]);
        }
        *(uint4*)&As[r][qc * 128 + c] = w.u;
    }

    const int wm = (wave >> 1) * 32, wn = (wave & 1) * 32;
    const int fr = lane & 15, fq = lane >> 4;
    float4v acc[2][2] = {};

    for (int k0 = 0; k0 < 512; k0 += 32) {
        __syncthreads();   // first iter: As writes; all iters: Bs reuse
        *(uint4*)&Bs[ar][ak] = b0;
        if (k0 + 32 < 512) b0 = *(const uint4*)(Bp + k0 + 32);
        __syncthreads();
        union { uint4 u; short8 s; } ua[2], ub[2];
        #pragma unroll
        for (int i = 0; i < 2; ++i) ua[i].u = *(const uint4*)&As[wm + i * 16 + fr][fq * 8 + k0];
        #pragma unroll
        for (int j = 0; j < 2; ++j) ub[j].u = *(const uint4*)&Bs[wn + j * 16 + fr][fq * 8];
        #pragma unroll
        for (int i = 0; i < 2; ++i)
            #pragma unroll
            for (int j = 0; j < 2; ++j)
                acc[i][j] = __builtin_amdgcn_mfma_f32_16x16x32_bf16(ua[i].s, ub[j].s, acc[i][j], 0, 0, 0);
    }

    #pragma unroll
    for (int i = 0; i < 2; ++i) {
        #pragma unroll
        for (int j = 0; j < 2; ++j) {
            #pragma unroll
            for (int rr = 0; rr < 4; ++rr) {
                int m = m0 + wm + i * 16 + fq * 4 + rr;
                int n = n0 + wn + j * 16 + fr;
                float v = acc[i][j][rr];
                if (EPI == 1) {
                    bf16* C = (bf16*)Cv;
                    if (n < 512) {
                        C[(size_t)m * ldc + n] = __float2bfloat16(v + ldsel(bias, biasoff + n, flg));
                    } else if (n < 1024) {
                        C[(size_t)m * ldc + n] = __float2bfloat16(v);
                    } else {
                        int h = (n >> 6) & 7, d = n & 63, ii = m & 1023, bb = m >> 10;
                        aux[(size_t)(bb * 8 + h) * 65536 + (size_t)d * 1024 + ii] = __float2bfloat16(v);
                    }
                } else if (EPI == 3) {
                    bf16* C = (bf16*)Cv;
                    float t = v + ldsel(bias, biasoff + n, flg);
                    C[(size_t)m * ldc + n] = __float2bfloat16(0.5f * t * (1.f + erff(t * 0.70710678118f)));
                }
            }
        }
    }
}

// ---- BD producer: P = (q . wsum)/3 for all 8 heads, rel-shift scatter into
// interleaved Scb[(t-1024)*8 + h]. Register-prefetch across the h-loop.
__global__ __launch_bounds__(512) void bd_kernel(
    const bf16* __restrict__ qkvb, const bf16* __restrict__ wsum,
    bf16* __restrict__ Scb) {
    const int tid = threadIdx.x;
    const int lane = tid & 63, wave = tid >> 6;
    const int n0 = blockIdx.x * 64, m0 = blockIdx.y * 64, b = blockIdx.z;

    __shared__ bf16 Qs[64][72];
    __shared__ bf16 Ws[64][72];

    const int r0 = tid >> 3, c0 = (tid & 7) * 8;
    const bf16* Qp = qkvb + (size_t)(b * 1024 + m0 + r0) * 1536 + c0;
    const bf16* Wp = wsum + (size_t)(b * 1024 + n0 + r0) * 512 + c0;

    const int wm = (wave >> 2) * 32, wn = (wave & 3) * 16;
    const int fr = lane & 15, fq = lane >> 4;

    float4v acc[8][2] = {};

    uint4 qreg = *(const uint4*)Qp;
    uint4 wreg = *(const uint4*)Wp;

    for (int h = 0; h < 8; ++h) {
        __syncthreads();
        *(uint4*)&Qs[r0][c0] = qreg;
        *(uint4*)&Ws[r0][c0] = wreg;
        if (h < 7) {
            qreg = *(const uint4*)(Qp + (h + 1) * 64);
            wreg = *(const uint4*)(Wp + (h + 1) * 64);
        }
        __syncthreads();
        #pragma unroll
        for (int ks = 0; ks < 2; ++ks) {
            union { uint4 u; short8 s; } ua[2], ub;
            #pragma unroll
            for (int i = 0; i < 2; ++i) ua[i].u = *(const uint4*)&Qs[wm + i * 16 + fr][fq * 8 + ks * 32];
            ub.u = *(const uint4*)&Ws[wn + fr][fq * 8 + ks * 32];
            #pragma unroll
            for (int i = 0; i < 2; ++i)
                acc[h][i] = __builtin_amdgcn_mfma_f32_16x16x32_bf16(ua[i].s, ub.s, acc[h][i], 0, 0, 0);
        }
    }

    const size_t pb = (size_t)b * 8388608;
    #pragma unroll
    for (int i = 0; i < 2; ++i) {
        #pragma unroll
        for (int r = 0; r < 4; ++r) {
            int m = m0 + wm + i * 16 + fq * 4 + r;
            int n = n0 + wn + fr;
            int t = m * 1025 + n + 1;
            if (t >= 1024) {
                short8 v;
                #pragma unroll
                for (int h = 0; h < 8; ++h) v[h] = f2bf(acc[h][i][r] * (1.f / 3.f));
                *(short8*)(Scb + pb + (size_t)(t - 1024) * 8) = v;
            }
        }
    }
}

// ---- fused AC + BD + softmax-over-h. 8 waves, 64x64 (i,j) tile. ----
__global__ __launch_bounds__(512) void scores_kernel(
    const bf16* __restrict__ qkvb, const bf16* __restrict__ Scb,
    bf16* __restrict__ attn) {
    const int tid = threadIdx.x;
    const int lane = tid & 63, wave = tid >> 6;
    const int j0 = blockIdx.x * 64, i0 = blockIdx.y * 64, b = blockIdx.z;

    __shared__ bf16 Qs[64][72];
    __shared__ bf16 Ks[64][72];

    const int r0 = tid >> 3, c0 = (tid & 7) * 8;
    const bf16* Qp = qkvb + (size_t)(b * 1024 + i0 + r0) * 1536 + c0;
    const bf16* Kp = qkvb + (size_t)(b * 1024 + j0 + r0) * 1536 + 512 + c0;

    const int wm = (wave >> 2) * 32, wn = (wave & 3) * 16;
    const int fr = lane & 15, fq = lane >> 4;

    float4v acc[8][2] = {};

    uint4 qreg = *(const uint4*)Qp;
    uint4 kreg = *(const uint4*)Kp;

    for (int h = 0; h < 8; ++h) {
        __syncthreads();
        *(uint4*)&Qs[r0][c0] = qreg;
        *(uint4*)&Ks[r0][c0] = kreg;
        if (h < 7) {
            qreg = *(const uint4*)(Qp + (h + 1) * 64);
            kreg = *(const uint4*)(Kp + (h + 1) * 64);
        }
        __syncthreads();
        #pragma unroll
        for (int ks = 0; ks < 2; ++ks) {
            union { uint4 u; short8 s; } ua[2], ub;
            #pragma unroll
            for (int i = 0; i < 2; ++i) ua[i].u = *(const uint4*)&Qs[wm + i * 16 + fr][fq * 8 + ks * 32];
            ub.u = *(const uint4*)&Ks[wn + fr][fq * 8 + ks * 32];
            #pragma unroll
            for (int i = 0; i < 2; ++i)
                acc[h][i] = __builtin_amdgcn_mfma_f32_16x16x32_bf16(ua[i].s, ub.s, acc[h][i], 0, 0, 0);
        }
    }

    // pass 1: per-element max + inv-sum over h (bd kept in registers)
    short8 bdv[8];
    float mxs[8], invs[8];
    const size_t pb = (size_t)b * 8388608;
    #pragma unroll
    for (int i = 0; i < 2; ++i) {
        #pragma unroll
        for (int r = 0; r < 4; ++r) {
            const int e = i * 4 + r;
            int gi = i0 + wm + i * 16 + fq * 4 + r;
            int gj = j0 + wn + fr;
            bdv[e] = *(const short8*)(Scb + pb + ((size_t)gi * 1024 + gj) * 8);
            bool diag = (gj == gi + 1);
            float dv[8];
            float mx = -3.4e38f;
            #pragma unroll
            for (int h = 0; h < 8; ++h) {
                float bd = diag ? 0.f : bf2f(bdv[e][h]);
                dv[h] = (acc[h][i][r] + bd) * 0.125f;
                mx = fmaxf(mx, dv[h]);
            }
            float s = 0.f;
            #pragma unroll
            for (int h = 0; h < 8; ++h) s += __expf(dv[h] - mx);
            mxs[e] = mx; invs[e] = 1.f / s;
        }
    }

    // pass 2: per h, stage 64x64 bf16 tile in LDS (Qs reused), write full rows.
    const size_t ab = (size_t)b * 8388608;
    const int orow = tid >> 3, ocol = (tid & 7) * 8;
    #pragma unroll
    for (int h = 0; h < 8; ++h) {
        __syncthreads();
        #pragma unroll
        for (int i = 0; i < 2; ++i) {
            #pragma unroll
            for (int r = 0; r < 4; ++r) {
                const int e = i * 4 + r;
                int gil = wm + i * 16 + fq * 4 + r;
                int gjl = wn + fr;
                int gi = i0 + gil, gj = j0 + gjl;
                float bd = (gj == gi + 1) ? 0.f : bf2f(bdv[e][h]);
                float a = __expf((acc[h][i][r] + bd) * 0.125f - mxs[e]) * invs[e];
                Qs[gil][gjl] = __float2bfloat16(a);
            }
        }
        __syncthreads();
        *(uint4*)(attn + ab + (size_t)h * 1048576 + (size_t)(i0 + orow) * 1024 + j0 + ocol)
            = *(const uint4*)&Qs[orow][ocol];
    }
}

extern "C" void kernel_launch(void* const* d_in, const int* in_sizes, int n_in,
                              void* d_out, int out_size, void* d_ws, size_t ws_size,
                              hipStream_t stream) {
    (void)in_sizes; (void)n_in; (void)out_size; (void)ws_size;
    const void* x_in    = d_in[0];
    const void* r_t     = d_in[1];
    const void* r_c     = d_in[2];
    const void* r_p     = d_in[3];
    const void* bias_pf = d_in[4];
    const void* ln1_g   = d_in[5];
    const void* ln1_b   = d_in[6];
    const void* w_qkv   = d_in[7];
    const void* w_outw  = d_in[8];
    const void* b_out   = d_in[9];
    const void* w_kt    = d_in[10];
    const void* w_kc    = d_in[11];
    const void* w_kp    = d_in[12];
    const void* ln2_g   = d_in[13];
    const void* ln2_b   = d_in[14];
    const void* w_ff1   = d_in[15];
    const void* b_ff1   = d_in[16];
    const void* w_ff2   = d_in[17];
    const void* b_ff2   = d_in[18];

    float* xbuf  = (float*)d_ws;                 // 1M fp32
    bf16* base16 = (bf16*)(xbuf + 1048576);
    bf16* Scb   = base16;                        // 16M (h1 aliases first 4M)
    bf16* h1    = base16;
    bf16* attn  = base16 + 16777216;             // 16M
    bf16* xnb   = attn + 16777216;               // 1M
    bf16* qkvb  = xnb + 1048576;                 // 3M
    bf16* vT    = qkvb + 3145728;                // 1M
    bf16* wsum4 = vT + 1048576;                  // 4M (all 4 layers)
    bf16* rcat  = wsum4 + 4194304;               // 3M
    bf16* arena = rcat + 3145728;                // 15.75M
    int*  flagp = (int*)(arena + 15728640);

    const int LW = 3932160;
    const int WCAT_O = 786432, OUT_O = 1572864, FF1_O = 1835008, FF2_O = 2883584;
    const int QKV_O = 0;

    dim3 blk(256), blk8(512);

    detect_kernel<<<1, 64, 0, stream>>>((const unsigned int*)ln1_g, flagp);
    input_prep<<<dim3(512, 4), blk, 0, stream>>>(x_in, r_t, r_c, r_p, xbuf, rcat, flagp);

    prep_weights<<<3840, blk, 0, stream>>>(
        w_qkv, w_kt, w_kc, w_kp, w_outw, w_ff1, w_ff2, arena, flagp);

    // wsum for ALL layers, batched (z = layer): wsum4[l] = rcat @ wcatT[l]^T
    mgemm64<5><<<dim3(8, 32, 4), blk, 0, stream>>>(
        rcat, 1536, 0, 0, arena + WCAT_O, 1536, 0, LW,
        wsum4, 512, 0, 1048576, 1536, nullptr, 0, nullptr, nullptr, flagp);

    for (int l = 0; l < 4; ++l) {
        const bf16* qkvT  = arena + l * LW + QKV_O;
        const bf16* outT  = arena + l * LW + OUT_O;
        const bf16* ff1T  = arena + l * LW + FF1_O;
        const bf16* ff2T  = arena + l * LW + FF2_O;
        const bf16* wsum  = wsum4 + (size_t)l * 1048576;

        // qkv = LN1(x) @ qkvT^T; q += bias_pf; v -> vT   (LN fused)
        mgemm_ln<1><<<dim3(24, 32), blk, 0, stream>>>(
            xbuf, ln1_g, l * 512, ln1_b, l * 512,
            qkvT, 512, qkvb, 1536, bias_pf, 0, vT, flagp);
        // Scb[(t-1024)*8+h] = rel_shift(q . wsum)/3, packed over h
        bd_kernel<<<dim3(16, 16, 2), blk8, 0, stream>>>(qkvb, wsum, Scb);
        // fused AC + BD + softmax -> attn
        scores_kernel<<<dim3(16, 16, 2), blk8, 0, stream>>>(qkvb, Scb, attn);
        // out = attn @ vT^T -> xnb
        mgemm64<5><<<dim3(1, 16, 16), blk, 0, stream>>>(
            attn, 1024, 8388608, 1048576, vT, 1024, 524288, 65536,
            xnb, 512, 524288, 64, 1024, nullptr, 0, nullptr, nullptr, flagp);
        // x = out @ outT^T + b_out + x (fp32)
        mgemm64<2><<<dim3(8, 32, 1), blk, 0, stream>>>(
            xnb, 512, 0, 0, outT, 512, 0, 0,
            xbuf, 512, 0, 0, 512, b_out, (long long)l * 512, xbuf, nullptr, flagp);
        // h1 = gelu(LN2(x) @ ff1T^T + b_ff1)   (LN fused)
        mgemm_ln<3><<<dim3(32, 32), blk, 0, stream>>>(
            xbuf, ln2_g, l * 512, ln2_b, l * 512,
            ff1T, 512, h1, 2048, b_ff1, (long long)l * 2048, nullptr, flagp);
        // x = h1 @ ff2T^T + b_ff2 + x (fp32)
        mgemm64<2><<<dim3(8, 32, 1), blk, 0, stream>>>(
            h1, 2048, 0, 0, ff2T, 2048, 0, 0,
            xbuf, 512, 0, 0, 2048, b_ff2, (long long)l * 512, xbuf, nullptr, flagp);
    }

    // x -> d_out[0..1M), attn -> d_out[1M..17M), one dispatch
    outputs_kernel<<<8704, blk, 0, stream>>>(xbuf, attn, d_out, flagp);
}

// Round 5
// 733.661 us; speedup vs baseline: 1.1792x; 1.1792x over previous
//
#include <hip/hip_runtime.h>
#include <hip/hip_bf16.h>

// B=2, N=1024, D=512, H=8, DH=64, HD=512, FF=2048, DEPTH=4.
// Dual-dtype IO (bf16 or fp32, runtime-detected from ln1_g word0).
// bf16 MFMA 16x16x32 everywhere, fp32 accum, fp32 residual chain.
// R5: LN folded algebraically — gamma into prepped weights (prep_weights),
//     beta into bias vectors (bvec_kernel, once); per-row stats (ln_stats);
//     mgemm64f stages fp32 A with (v-mean)*rstd (small LDS, conflict-free).
//     R4's resident-tile mgemm_ln removed (bank conflicts + redundant LN).

using bf16 = __hip_bfloat16;
typedef __attribute__((ext_vector_type(8))) short short8;
typedef __attribute__((ext_vector_type(4))) float float4v;
typedef __attribute__((ext_vector_type(2))) unsigned int uint2v;

__device__ __forceinline__ float ldsel(const void* p, long long i, bool isbf) {
    return isbf ? __bfloat162float(((const bf16*)p)[i]) : ((const float*)p)[i];
}
__device__ __forceinline__ float bf2f(short u) {
    return __uint_as_float(((unsigned)(unsigned short)u) << 16);
}
__device__ __forceinline__ short f2bf(float f) {
    bf16 h = __float2bfloat16(f);
    return *reinterpret_cast<short*>(&h);
}

__global__ void detect_kernel(const unsigned int* __restrict__ g, int* __restrict__ flag) {
    if (threadIdx.x == 0) flag[0] = ((g[0] & 0xFFFFu) != 0u) ? 1 : 0;
}

// y==0: cast x_in -> xbuf (fp32). y==1..3: rcat plane.
__global__ __launch_bounds__(256) void input_prep(
    const void* __restrict__ x_in, const void* __restrict__ r0,
    const void* __restrict__ r1, const void* __restrict__ r2,
    float* __restrict__ xbuf, bf16* __restrict__ rcat,
    const int* __restrict__ flagp) {
    bool bf = flagp[0] != 0;
    int y = blockIdx.y;
    int i = blockIdx.x * 256 + threadIdx.x;          // 0..131071
    if (y == 0) {
        long long b = (long long)i * 8;
        if (bf) {
            short8 v = *(const short8*)((const bf16*)x_in + b);
            float4v o0, o1;
            #pragma unroll
            for (int j = 0; j < 4; ++j) { o0[j] = bf2f(v[j]); o1[j] = bf2f(v[4 + j]); }
            *(float4v*)(xbuf + b) = o0;
            *(float4v*)(xbuf + b + 4) = o1;
        } else {
            float4v a0 = *(const float4v*)((const float*)x_in + b);
            float4v a1 = *(const float4v*)((const float*)x_in + b + 4);
            *(float4v*)(xbuf + b) = a0;
            *(float4v*)(xbuf + b + 4) = a1;
        }
    } else {
        int s = y - 1;
        const void* src = (s == 0) ? r0 : ((s == 1) ? r1 : r2);
        int m = i >> 6, k8 = (i & 63) * 8;
        long long b = (long long)m * 512 + k8;
        short8 v;
        if (bf) {
            v = *(const short8*)((const bf16*)src + b);
        } else {
            float4v a0 = *(const float4v*)((const float*)src + b);
            float4v a1 = *(const float4v*)((const float*)src + b + 4);
            #pragma unroll
            for (int j = 0; j < 4; ++j) { v[j] = f2bf(a0[j]); v[4 + j] = f2bf(a1[j]); }
        }
        *(short8*)(rcat + (size_t)m * 1536 + s * 512 + k8) = v;
    }
}

// blocks [0,512): xbuf -> d_out x-region. blocks [512,8704): attn -> d_out.
__global__ __launch_bounds__(256) void outputs_kernel(
    const float* __restrict__ xbuf, const bf16* __restrict__ attn,
    void* __restrict__ out, const int* __restrict__ flagp) {
    bool bf = flagp[0] != 0;
    int bid = blockIdx.x;
    if (bid < 512) {
        long long b = ((long long)bid * 256 + threadIdx.x) * 8;
        float4v a0 = *(const float4v*)(xbuf + b);
        float4v a1 = *(const float4v*)(xbuf + b + 4);
        if (bf) {
            short8 v;
            #pragma unroll
            for (int j = 0; j < 4; ++j) { v[j] = f2bf(a0[j]); v[4 + j] = f2bf(a1[j]); }
            *(short8*)((bf16*)out + b) = v;
        } else {
            *(float4v*)((float*)out + b) = a0;
            *(float4v*)((float*)out + b + 4) = a1;
        }
    } else {
        long long e = ((long long)(bid - 512) * 256 + threadIdx.x) * 8;  // < 16777216
        short8 v = *(const short8*)(attn + e);
        if (bf) {
            *(short8*)((bf16*)out + 1048576 + e) = v;
        } else {
            float4v o0, o1;
            #pragma unroll
            for (int j = 0; j < 4; ++j) { o0[j] = bf2f(v[j]); o1[j] = bf2f(v[4 + j]); }
            float* op = (float*)out + 1048576 + e;
            *(float4v*)op = o0;
            *(float4v*)(op + 4) = o1;
        }
    }
}

// ---- all weight transposes (all 4 layers) in ONE exact-sized dispatch ----
// qkvT rows scaled by ln1_g[k]; ff1T rows scaled by ln2_g[k] (gamma fold).
__global__ __launch_bounds__(256) void prep_weights(
    const void* __restrict__ s0, const void* __restrict__ s1, const void* __restrict__ s2,
    const void* __restrict__ s3, const void* __restrict__ s4, const void* __restrict__ s5,
    const void* __restrict__ s6, const void* __restrict__ g1, const void* __restrict__ g2,
    bf16* __restrict__ arena, const int* __restrict__ flagp) {
    const bool bf = flagp[0] != 0;
    const int bid = blockIdx.x;
    const int l = bid / 960;
    const int rem = bid - l * 960;
    const int LW = 3932160;
    const int L = l * LW;

    int j, tile, tx, ldi, ldo;
    long long ioff;
    int dstoff;
    if (rem < 192)      { j = 0; tile = rem;                tx = 24; ldi = 1536; ldo = 512;
                          ioff = (long long)l * 786432;  dstoff = L; }
    else if (rem < 448) { j = 1 + ((rem - 192) >> 6); tile = (rem - 192) & 63; tx = 8; ldi = 512;
                          ioff = (long long)l * 262144;
                          if (j <= 3) { ldo = 1536; dstoff = L + 786432 + (j - 1) * 512; }
                          else        { ldo = 512;  dstoff = L + 1572864; } }
    else if (rem < 704) { j = 5; tile = rem - 448;          tx = 32; ldi = 2048; ldo = 512;
                          ioff = (long long)l * 1048576; dstoff = L + 1835008; }
    else                { j = 6; tile = rem - 704;          tx = 8;  ldi = 512;  ldo = 2048;
                          ioff = (long long)l * 1048576; dstoff = L + 2883584; }
    const void* in = (j == 0) ? s0 : (j == 1) ? s1 : (j == 2) ? s2 :
                     (j == 3) ? s3 : (j == 4) ? s4 : (j == 5) ? s5 : s6;
    const int gsel = (j == 0) ? 1 : ((j == 5) ? 2 : 0);
    bf16* out = arena + dstoff;
    const int bx = tile % tx, by = tile / tx;
    const int n0 = bx * 64, k0 = by * 64;
    const int tid = threadIdx.x;

    __shared__ bf16 t[64][72];

    if (bf) {
        const bf16* inb = (const bf16*)in + ioff;
        #pragma unroll
        for (int p = 0; p < 2; ++p) {
            int e = tid + p * 256;
            int r = e >> 3, c = (e & 7) * 8;
            *(uint4*)&t[r][c] = *(const uint4*)(inb + (size_t)(k0 + r) * ldi + n0 + c);
        }
    } else {
        const float* inf = (const float*)in + ioff;
        #pragma unroll
        for (int p = 0; p < 4; ++p) {
            int e = tid + p * 256;
            int r = e >> 4, c = (e & 15) * 4;
            float4v v = *(const float4v*)(inf + (size_t)(k0 + r) * ldi + n0 + c);
            union { bf16 h[4]; uint2v u; } w;
            #pragma unroll
            for (int q = 0; q < 4; ++q) w.h[q] = __float2bfloat16(v[q]);
            *reinterpret_cast<uint2v*>(&t[r][c]) = w.u;
        }
    }
    __syncthreads();
    #pragma unroll
    for (int p = 0; p < 2; ++p) {
        int e = tid + p * 256;
        int r = e >> 3, c = (e & 7) * 8;
        union { short8 s; uint4 u; } o;
        if (gsel) {
            const void* gp = (gsel == 1) ? g1 : g2;
            const long long go = (long long)l * 512 + k0 + c;
            #pragma unroll
            for (int q = 0; q < 8; ++q) {
                float gv = ldsel(gp, go + q, bf);
                o.s[q] = f2bf(bf2f(*reinterpret_cast<const short*>(&t[c + q][r])) * gv);
            }
        } else {
            #pragma unroll
            for (int q = 0; q < 8; ++q)
                o.s[q] = *reinterpret_cast<const short*>(&t[c + q][r]);
        }
        *(uint4*)(out + (size_t)(n0 + r) * ldo + k0 + c) = o.u;
    }
}

// ---- beta fold: bB[n] = sum_k beta[k]*W[k,n] (+ bias_pf / b_ff1). Once. ----
// 56 blocks: per layer 14 = 6 qkv col-blocks (1536) + 8 ff1 col-blocks (2048).
__global__ __launch_bounds__(256) void bvec_kernel(
    const void* __restrict__ w_qkv, const void* __restrict__ w_ff1,
    const void* __restrict__ ln1_b, const void* __restrict__ ln2_b,
    const void* __restrict__ bias_pf, const void* __restrict__ b_ff1,
    float* __restrict__ bBq, float* __restrict__ bBf,
    const int* __restrict__ flagp) {
    bool bf = flagp[0] != 0;
    int bid = blockIdx.x;
    int l = bid / 14, r = bid - l * 14;
    int tid = threadIdx.x;
    __shared__ float bs[512];

    const void* W; long long woff; int ldw, n0; const void* beta; float* out;
    if (r < 6) { W = w_qkv; woff = (long long)l * 786432;  ldw = 1536; n0 = r * 256;
                 beta = ln1_b; out = bBq + l * 1536; }
    else       { W = w_ff1; woff = (long long)l * 1048576; ldw = 2048; n0 = (r - 6) * 256;
                 beta = ln2_b; out = bBf + l * 2048; }
    long long boff = (long long)l * 512;
    bs[tid]       = ldsel(beta, boff + tid, bf);
    bs[tid + 256] = ldsel(beta, boff + tid + 256, bf);
    __syncthreads();
    float acc = 0.f;
    #pragma unroll 8
    for (int k = 0; k < 512; ++k)
        acc += bs[k] * ldsel(W, woff + (long long)k * ldw + n0 + tid, bf);
    int n = n0 + tid;
    if (r < 6) { if (n < 512) acc += ldsel(bias_pf, n, bf); }
    else       { acc += ldsel(b_ff1, (long long)l * 2048 + n, bf); }
    out[n] = acc;
}

// ---- per-row LN stats: mean + rstd -> stats[row] ----
__global__ __launch_bounds__(256) void ln_stats(const float* __restrict__ x,
                                                float2* __restrict__ st) {
    int row = blockIdx.x;
    const float* xr = x + (size_t)row * 512;
    int tid = threadIdx.x;
    float v0 = xr[tid], v1 = xr[tid + 256];
    float s = v0 + v1, q = v0 * v0 + v1 * v1;
    #pragma unroll
    for (int off = 32; off; off >>= 1) {
        s += __shfl_down(s, off);
        q += __shfl_down(q, off);
    }
    __shared__ float ls[4], lq[4];
    int wid = tid >> 6, lane = tid & 63;
    if (lane == 0) { ls[wid] = s; lq[wid] = q; }
    __syncthreads();
    if (tid == 0) {
        float ts = ls[0] + ls[1] + ls[2] + ls[3];
        float tq = lq[0] + lq[1] + lq[2] + lq[3];
        float m = ts * (1.f / 512.f);
        float var = tq * (1.f / 512.f) - m * m;
        st[row] = make_float2(m, rsqrtf(var + 1e-5f));
    }
}

// ---- MFMA GEMM 64x64 tile (4 waves, 32x32 per wave), bf16 A ----
// EPI: 2 fp32 +bias+resid; 5 bf16 plain store.
template<int EPI>
__global__ __launch_bounds__(256) void mgemm64(
    const bf16* __restrict__ A, int lda, long long sAb, long long sAh,
    const bf16* __restrict__ B, int ldb, long long sBb, long long sBh,
    void* __restrict__ Cv, int ldc, long long sCb, long long sCh,
    int K,
    const void* __restrict__ bias, long long biasoff,
    float* __restrict__ resid,
    const int* __restrict__ flagp) {
    const bool flg = flagp[0] != 0;
    const int tid = threadIdx.x;
    const int lane = tid & 63, wave = tid >> 6;
    const int m0 = blockIdx.y * 64, n0 = blockIdx.x * 64;
    const int zb = (int)(blockIdx.z >> 3), zh = (int)(blockIdx.z & 7);
    A += (size_t)zb * sAb + (size_t)zh * sAh;
    B += (size_t)zb * sBb + (size_t)zh * sBh;

    __shared__ bf16 As[64][40];
    __shared__ bf16 Bs[64][40];

    const int ar = tid >> 2, ak = (tid & 3) * 8;
    const bf16* Ap = A + (size_t)(m0 + ar) * lda + ak;
    const bf16* Bp = B + (size_t)(n0 + ar) * ldb + ak;

    const int wm = (wave >> 1) * 32, wn = (wave & 1) * 32;
    const int fr = lane & 15, fq = lane >> 4;

    float4v acc[2][2] = {};

    uint4 a0 = *(const uint4*)Ap;
    uint4 b0 = *(const uint4*)Bp;

    for (int k0 = 0; k0 < K; k0 += 32) {
        __syncthreads();
        *(uint4*)&As[ar][ak] = a0;
        *(uint4*)&Bs[ar][ak] = b0;
        if (k0 + 32 < K) {
            a0 = *(const uint4*)(Ap + k0 + 32);
            b0 = *(const uint4*)(Bp + k0 + 32);
        }
        __syncthreads();
        union { uint4 u; short8 s; } ua[2], ub[2];
        #pragma unroll
        for (int i = 0; i < 2; ++i) ua[i].u = *(const uint4*)&As[wm + i * 16 + fr][fq * 8];
        #pragma unroll
        for (int j = 0; j < 2; ++j) ub[j].u = *(const uint4*)&Bs[wn + j * 16 + fr][fq * 8];
        #pragma unroll
        for (int i = 0; i < 2; ++i)
            #pragma unroll
            for (int j = 0; j < 2; ++j)
                acc[i][j] = __builtin_amdgcn_mfma_f32_16x16x32_bf16(ua[i].s, ub[j].s, acc[i][j], 0, 0, 0);
    }

    const long long coff = (long long)zb * sCb + (long long)zh * sCh;
    #pragma unroll
    for (int i = 0; i < 2; ++i) {
        #pragma unroll
        for (int j = 0; j < 2; ++j) {
            #pragma unroll
            for (int r = 0; r < 4; ++r) {
                int m = m0 + wm + i * 16 + fq * 4 + r;
                int n = n0 + wn + j * 16 + fr;
                float v = acc[i][j][r];
                if (EPI == 2) {
                    float* C = (float*)Cv;
                    C[(size_t)m * ldc + n] = v + ldsel(bias, biasoff + n, flg) + resid[(size_t)m * ldc + n];
                } else if (EPI == 5) {
                    bf16* C = (bf16*)Cv + coff;
                    C[(size_t)m * ldc + n] = __float2bfloat16(v);
                }
            }
        }
    }
}

// ---- LN-fused GEMM, done right: fp32 A, per-row stats applied in staging.
// B is gamma-folded; bB[n] = beta-dot (+ extra bias). K=512, lda=512 fixed.
// EPI: 1 = qkv epilogue (qkvb + vT scatter), 3 = gelu bf16 store.
template<int EPI>
__global__ __launch_bounds__(256) void mgemm64f(
    const float* __restrict__ A, const float2* __restrict__ stats,
    const bf16* __restrict__ B, int ldb,
    void* __restrict__ Cv, int ldc,
    const float* __restrict__ bB,
    bf16* __restrict__ aux) {
    const int tid = threadIdx.x;
    const int lane = tid & 63, wave = tid >> 6;
    const int m0 = blockIdx.y * 64, n0 = blockIdx.x * 64;

    __shared__ bf16 As[64][40];
    __shared__ bf16 Bs[64][40];

    const int ar = tid >> 2, ak = (tid & 3) * 8;
    const float* Ap = A + (size_t)(m0 + ar) * 512 + ak;
    const bf16* Bp  = B + (size_t)(n0 + ar) * ldb + ak;
    const float2 st = stats[m0 + ar];

    const int wm = (wave >> 1) * 32, wn = (wave & 1) * 32;
    const int fr = lane & 15, fq = lane >> 4;

    float4v acc[2][2] = {};

    float4v af0 = *(const float4v*)Ap;
    float4v af1 = *(const float4v*)(Ap + 4);
    uint4 b0 = *(const uint4*)Bp;

    for (int k0 = 0; k0 < 512; k0 += 32) {
        __syncthreads();
        union { bf16 h[8]; uint4 u; } w;
        #pragma unroll
        for (int u = 0; u < 4; ++u) {
            w.h[u]     = __float2bfloat16((af0[u] - st.x) * st.y);
            w.h[4 + u] = __float2bfloat16((af1[u] - st.x) * st.y);
        }
        *(uint4*)&As[ar][ak] = w.u;
        *(uint4*)&Bs[ar][ak] = b0;
        if (k0 + 32 < 512) {
            af0 = *(const float4v*)(Ap + k0 + 32);
            af1 = *(const float4v*)(Ap + k0 + 36);
            b0  = *(const uint4*)(Bp + k0 + 32);
        }
        __syncthreads();
        union { uint4 u; short8 s; } ua[2], ub[2];
        #pragma unroll
        for (int i = 0; i < 2; ++i) ua[i].u = *(const uint4*)&As[wm + i * 16 + fr][fq * 8];
        #pragma unroll
        for (int j = 0; j < 2; ++j) ub[j].u = *(const uint4*)&Bs[wn + j * 16 + fr][fq * 8];
        #pragma unroll
        for (int i = 0; i < 2; ++i)
            #pragma unroll
            for (int j = 0; j < 2; ++j)
                acc[i][j] = __builtin_amdgcn_mfma_f32_16x16x32_bf16(ua[i].s, ub[j].s, acc[i][j], 0, 0, 0);
    }

    #pragma unroll
    for (int i = 0; i < 2; ++i) {
        #pragma unroll
        for (int j = 0; j < 2; ++j) {
            #pragma unroll
            for (int r = 0; r < 4; ++r) {
                int m = m0 + wm + i * 16 + fq * 4 + r;
                int n = n0 + wn + j * 16 + fr;
                float v = acc[i][j][r] + bB[n];
                if (EPI == 1) {
                    bf16* C = (bf16*)Cv;
                    if (n < 1024) {
                        C[(size_t)m * ldc + n] = __float2bfloat16(v);
                    } else {
                        int h = (n >> 6) & 7, d = n & 63, ii = m & 1023, bb = m >> 10;
                        aux[(size_t)(bb * 8 + h) * 65536 + (size_t)d * 1024 + ii] = __float2bfloat16(v);
                    }
                } else if (EPI == 3) {
                    bf16* C = (bf16*)Cv;
                    C[(size_t)m * ldc + n] = __float2bfloat16(0.5f * v * (1.f + erff(v * 0.70710678118f)));
                }
            }
        }
    }
}

// ---- BD producer: P = (q . wsum)/3 for all 8 heads, rel-shift scatter into
// interleaved Scb[(t-1024)*8 + h]. Register-prefetch across the h-loop.
__global__ __launch_bounds__(512) void bd_kernel(
    const bf16* __restrict__ qkvb, const bf16* __restrict__ wsum,
    bf16* __restrict__ Scb) {
    const int tid = threadIdx.x;
    const int lane = tid & 63, wave = tid >> 6;
    const int n0 = blockIdx.x * 64, m0 = blockIdx.y * 64, b = blockIdx.z;

    __shared__ bf16 Qs[64][72];
    __shared__ bf16 Ws[64][72];

    const int r0 = tid >> 3, c0 = (tid & 7) * 8;
    const bf16* Qp = qkvb + (size_t)(b * 1024 + m0 + r0) * 1536 + c0;
    const bf16* Wp = wsum + (size_t)(b * 1024 + n0 + r0) * 512 + c0;

    const int wm = (wave >> 2) * 32, wn = (wave & 3) * 16;
    const int fr = lane & 15, fq = lane >> 4;

    float4v acc[8][2] = {};

    uint4 qreg = *(const uint4*)Qp;
    uint4 wreg = *(const uint4*)Wp;

    for (int h = 0; h < 8; ++h) {
        __syncthreads();
        *(uint4*)&Qs[r0][c0] = qreg;
        *(uint4*)&Ws[r0][c0] = wreg;
        if (h < 7) {
            qreg = *(const uint4*)(Qp + (h + 1) * 64);
            wreg = *(const uint4*)(Wp + (h + 1) * 64);
        }
        __syncthreads();
        #pragma unroll
        for (int ks = 0; ks < 2; ++ks) {
            union { uint4 u; short8 s; } ua[2], ub;
            #pragma unroll
            for (int i = 0; i < 2; ++i) ua[i].u = *(const uint4*)&Qs[wm + i * 16 + fr][fq * 8 + ks * 32];
            ub.u = *(const uint4*)&Ws[wn + fr][fq * 8 + ks * 32];
            #pragma unroll
            for (int i = 0; i < 2; ++i)
                acc[h][i] = __builtin_amdgcn_mfma_f32_16x16x32_bf16(ua[i].s, ub.s, acc[h][i], 0, 0, 0);
        }
    }

    const size_t pb = (size_t)b * 8388608;
    #pragma unroll
    for (int i = 0; i < 2; ++i) {
        #pragma unroll
        for (int r = 0; r < 4; ++r) {
            int m = m0 + wm + i * 16 + fq * 4 + r;
            int n = n0 + wn + fr;
            int t = m * 1025 + n + 1;
            if (t >= 1024) {
                short8 v;
                #pragma unroll
                for (int h = 0; h < 8; ++h) v[h] = f2bf(acc[h][i][r] * (1.f / 3.f));
                *(short8*)(Scb + pb + (size_t)(t - 1024) * 8) = v;
            }
        }
    }
}

// ---- fused AC + BD + softmax-over-h. 8 waves, 64x64 (i,j) tile. ----
__global__ __launch_bounds__(512) void scores_kernel(
    const bf16* __restrict__ qkvb, const bf16* __restrict__ Scb,
    bf16* __restrict__ attn) {
    const int tid = threadIdx.x;
    const int lane = tid & 63, wave = tid >> 6;
    const int j0 = blockIdx.x * 64, i0 = blockIdx.y * 64, b = blockIdx.z;

    __shared__ bf16 Qs[64][72];
    __shared__ bf16 Ks[64][72];

    const int r0 = tid >> 3, c0 = (tid & 7) * 8;
    const bf16* Qp = qkvb + (size_t)(b * 1024 + i0 + r0) * 1536 + c0;
    const bf16* Kp = qkvb + (size_t)(b * 1024 + j0 + r0) * 1536 + 512 + c0;

    const int wm = (wave >> 2) * 32, wn = (wave & 3) * 16;
    const int fr = lane & 15, fq = lane >> 4;

    float4v acc[8][2] = {};

    uint4 qreg = *(const uint4*)Qp;
    uint4 kreg = *(const uint4*)Kp;

    for (int h = 0; h < 8; ++h) {
        __syncthreads();
        *(uint4*)&Qs[r0][c0] = qreg;
        *(uint4*)&Ks[r0][c0] = kreg;
        if (h < 7) {
            qreg = *(const uint4*)(Qp + (h + 1) * 64);
            kreg = *(const uint4*)(Kp + (h + 1) * 64);
        }
        __syncthreads();
        #pragma unroll
        for (int ks = 0; ks < 2; ++ks) {
            union { uint4 u; short8 s; } ua[2], ub;
            #pragma unroll
            for (int i = 0; i < 2; ++i) ua[i].u = *(const uint4*)&Qs[wm + i * 16 + fr][fq * 8 + ks * 32];
            ub.u = *(const uint4*)&Ks[wn + fr][fq * 8 + ks * 32];
            #pragma unroll
            for (int i = 0; i < 2; ++i)
                acc[h][i] = __builtin_amdgcn_mfma_f32_16x16x32_bf16(ua[i].s, ub.s, acc[h][i], 0, 0, 0);
        }
    }

    // pass 1: per-element max + inv-sum over h (bd kept in registers)
    short8 bdv[8];
    float mxs[8], invs[8];
    const size_t pb = (size_t)b * 8388608;
    #pragma unroll
    for (int i = 0; i < 2; ++i) {
        #pragma unroll
        for (int r = 0; r < 4; ++r) {
            const int e = i * 4 + r;
            int gi = i0 + wm + i * 16 + fq * 4 + r;
            int gj = j0 + wn + fr;
            bdv[e] = *(const short8*)(Scb + pb + ((size_t)gi * 1024 + gj) * 8);
            bool diag = (gj == gi + 1);
            float dv[8];
            float mx = -3.4e38f;
            #pragma unroll
            for (int h = 0; h < 8; ++h) {
                float bd = diag ? 0.f : bf2f(bdv[e][h]);
                dv[h] = (acc[h][i][r] + bd) * 0.125f;
                mx = fmaxf(mx, dv[h]);
            }
            float s = 0.f;
            #pragma unroll
            for (int h = 0; h < 8; ++h) s += __expf(dv[h] - mx);
            mxs[e] = mx; invs[e] = 1.f / s;
        }
    }

    // pass 2: per h, stage 64x64 bf16 tile in LDS (Qs reused), write full rows.
    const size_t ab = (size_t)b * 8388608;
    const int orow = tid >> 3, ocol = (tid & 7) * 8;
    #pragma unroll
    for (int h = 0; h < 8; ++h) {
        __syncthreads();
        #pragma unroll
        for (int i = 0; i < 2; ++i) {
            #pragma unroll
            for (int r = 0; r < 4; ++r) {
                const int e = i * 4 + r;
                int gil = wm + i * 16 + fq * 4 + r;
                int gjl = wn + fr;
                int gi = i0 + gil, gj = j0 + gjl;
                float bd = (gj == gi + 1) ? 0.f : bf2f(bdv[e][h]);
                float a = __expf((acc[h][i][r] + bd) * 0.125f - mxs[e]) * invs[e];
                Qs[gil][gjl] = __float2bfloat16(a);
            }
        }
        __syncthreads();
        *(uint4*)(attn + ab + (size_t)h * 1048576 + (size_t)(i0 + orow) * 1024 + j0 + ocol)
            = *(const uint4*)&Qs[orow][ocol];
    }
}

extern "C" void kernel_launch(void* const* d_in, const int* in_sizes, int n_in,
                              void* d_out, int out_size, void* d_ws, size_t ws_size,
                              hipStream_t stream) {
    (void)in_sizes; (void)n_in; (void)out_size; (void)ws_size;
    const void* x_in    = d_in[0];
    const void* r_t     = d_in[1];
    const void* r_c     = d_in[2];
    const void* r_p     = d_in[3];
    const void* bias_pf = d_in[4];
    const void* ln1_g   = d_in[5];
    const void* ln1_b   = d_in[6];
    const void* w_qkv   = d_in[7];
    const void* w_outw  = d_in[8];
    const void* b_out   = d_in[9];
    const void* w_kt    = d_in[10];
    const void* w_kc    = d_in[11];
    const void* w_kp    = d_in[12];
    const void* ln2_g   = d_in[13];
    const void* ln2_b   = d_in[14];
    const void* w_ff1   = d_in[15];
    const void* b_ff1   = d_in[16];
    const void* w_ff2   = d_in[17];
    const void* b_ff2   = d_in[18];

    float* xbuf  = (float*)d_ws;                 // 1M fp32
    bf16* base16 = (bf16*)(xbuf + 1048576);
    bf16* Scb   = base16;                        // 16M (h1 aliases first 4M)
    bf16* h1    = base16;
    bf16* attn  = base16 + 16777216;             // 16M
    bf16* xnb   = attn + 16777216;               // 1M
    bf16* qkvb  = xnb + 1048576;                 // 3M
    bf16* vT    = qkvb + 3145728;                // 1M
    bf16* wsum4 = vT + 1048576;                  // 4M (all 4 layers)
    bf16* rcat  = wsum4 + 4194304;               // 3M
    bf16* arena = rcat + 3145728;                // 15.75M
    int*   flagp = (int*)(arena + 15728640);
    float* bBq4  = (float*)(flagp + 16);         // 4*1536
    float* bBf4  = bBq4 + 6144;                  // 4*2048
    float2* stats = (float2*)(bBf4 + 8192);      // 2048 float2

    const int LW = 3932160;
    const int WCAT_O = 786432, OUT_O = 1572864, FF1_O = 1835008, FF2_O = 2883584;
    const int QKV_O = 0;

    dim3 blk(256), blk8(512);

    detect_kernel<<<1, 64, 0, stream>>>((const unsigned int*)ln1_g, flagp);
    input_prep<<<dim3(512, 4), blk, 0, stream>>>(x_in, r_t, r_c, r_p, xbuf, rcat, flagp);

    prep_weights<<<3840, blk, 0, stream>>>(
        w_qkv, w_kt, w_kc, w_kp, w_outw, w_ff1, w_ff2, ln1_g, ln2_g, arena, flagp);

    bvec_kernel<<<56, blk, 0, stream>>>(
        w_qkv, w_ff1, ln1_b, ln2_b, bias_pf, b_ff1, bBq4, bBf4, flagp);

    // wsum for ALL layers, batched (z = layer): wsum4[l] = rcat @ wcatT[l]^T
    mgemm64<5><<<dim3(8, 32, 4), blk, 0, stream>>>(
        rcat, 1536, 0, 0, arena + WCAT_O, 1536, 0, LW,
        wsum4, 512, 0, 1048576, 1536, nullptr, 0, nullptr, flagp);

    for (int l = 0; l < 4; ++l) {
        const bf16* qkvT  = arena + l * LW + QKV_O;
        const bf16* outT  = arena + l * LW + OUT_O;
        const bf16* ff1T  = arena + l * LW + FF1_O;
        const bf16* ff2T  = arena + l * LW + FF2_O;
        const bf16* wsum  = wsum4 + (size_t)l * 1048576;

        // LN1 stats
        ln_stats<<<2048, blk, 0, stream>>>(xbuf, stats);
        // qkv = LN1(x) @ (g1.qkvT)^T + bBq; q += bias_pf (folded); v -> vT
        mgemm64f<1><<<dim3(24, 32), blk, 0, stream>>>(
            xbuf, stats, qkvT, 512, qkvb, 1536, bBq4 + l * 1536, vT);
        // Scb[(t-1024)*8+h] = rel_shift(q . wsum)/3, packed over h
        bd_kernel<<<dim3(16, 16, 2), blk8, 0, stream>>>(qkvb, wsum, Scb);
        // fused AC + BD + softmax -> attn
        scores_kernel<<<dim3(16, 16, 2), blk8, 0, stream>>>(qkvb, Scb, attn);
        // out = attn @ vT^T -> xnb
        mgemm64<5><<<dim3(1, 16, 16), blk, 0, stream>>>(
            attn, 1024, 8388608, 1048576, vT, 1024, 524288, 65536,
            xnb, 512, 524288, 64, 1024, nullptr, 0, nullptr, flagp);
        // x = out @ outT^T + b_out + x (fp32)
        mgemm64<2><<<dim3(8, 32, 1), blk, 0, stream>>>(
            xnb, 512, 0, 0, outT, 512, 0, 0,
            xbuf, 512, 0, 0, 512, b_out, (long long)l * 512, xbuf, flagp);
        // LN2 stats
        ln_stats<<<2048, blk, 0, stream>>>(xbuf, stats);
        // h1 = gelu(LN2(x) @ (g2.ff1T)^T + bBf)
        mgemm64f<3><<<dim3(32, 32), blk, 0, stream>>>(
            xbuf, stats, ff1T, 512, h1, 2048, bBf4 + l * 2048, nullptr);
        // x = h1 @ ff2T^T + b_ff2 + x (fp32)
        mgemm64<2><<<dim3(8, 32, 1), blk, 0, stream>>>(
            h1, 2048, 0, 0, ff2T, 2048, 0, 0,
            xbuf, 512, 0, 0, 2048, b_ff2, (long long)l * 512, xbuf, flagp);
    }

    // x -> d_out[0..1M), attn -> d_out[1M..17M), one dispatch
    outputs_kernel<<<8704, blk, 0, stream>>>(xbuf, attn, d_out, flagp);
}

// Round 6
// 683.360 us; speedup vs baseline: 1.2659x; 1.0736x over previous
//
#include <hip/hip_runtime.h>
#include <hip/hip_bf16.h>

// B=2, N=1024, D=512, H=8, DH=64, HD=512, FF=2048, DEPTH=4.
// Dual-dtype IO (bf16 or fp32, runtime-detected from ln1_g word0).
// bf16 MFMA 16x16x32 everywhere, fp32 accum, fp32 residual chain.
// R6: bvec_kernel deleted -> beta-dot folded into prep_weights (LDS tile
//     reuse + atomicAdd, init_kernel preloads bias); ln_stats deleted ->
//     row (sum,sumsq) produced by input_prep (wave=row, direct store) and
//     by mgemm64<2> epilogues (shfl reduce + atomicAdd into st8[stage]);
//     mgemm64f computes mean/rstd inline from raw sums.

using bf16 = __hip_bfloat16;
typedef __attribute__((ext_vector_type(8))) short short8;
typedef __attribute__((ext_vector_type(4))) float float4v;
typedef __attribute__((ext_vector_type(2))) unsigned int uint2v;

__device__ __forceinline__ float ldsel(const void* p, long long i, bool isbf) {
    return isbf ? __bfloat162float(((const bf16*)p)[i]) : ((const float*)p)[i];
}
__device__ __forceinline__ float bf2f(short u) {
    return __uint_as_float(((unsigned)(unsigned short)u) << 16);
}
__device__ __forceinline__ short f2bf(float f) {
    bf16 h = __float2bfloat16(f);
    return *reinterpret_cast<short*>(&h);
}

__global__ void detect_kernel(const unsigned int* __restrict__ g, int* __restrict__ flag) {
    if (threadIdx.x == 0) flag[0] = ((g[0] & 0xFFFFu) != 0u) ? 1 : 0;
}

// zero st8 (9*2048 float2 = 36864 floats) + preload bB with bias_pf/b_ff1.
__global__ __launch_bounds__(256) void init_kernel(
    const void* __restrict__ bias_pf, const void* __restrict__ b_ff1,
    float* __restrict__ bBq, float* __restrict__ bBf, float* __restrict__ stz,
    const int* __restrict__ flagp) {
    bool bf = flagp[0] != 0;
    int idx = blockIdx.x * 256 + threadIdx.x;
    if (idx < 36864) { stz[idx] = 0.f; return; }
    int j = idx - 36864;
    if (j < 6144) {
        int n = j % 1536;
        bBq[j] = (n < 512) ? ldsel(bias_pf, n, bf) : 0.f;
    } else if (j < 14336) {
        int jj = j - 6144;              // = l*2048 + n, matches b_ff1 layout
        bBf[jj] = ldsel(b_ff1, jj, bf);
    }
}

// y==0: cast x_in -> xbuf (fp32) + row stats -> st0. y==1..3: rcat plane.
__global__ __launch_bounds__(256) void input_prep(
    const void* __restrict__ x_in, const void* __restrict__ r0,
    const void* __restrict__ r1, const void* __restrict__ r2,
    float* __restrict__ xbuf, bf16* __restrict__ rcat,
    float2* __restrict__ st0, const int* __restrict__ flagp) {
    bool bf = flagp[0] != 0;
    int y = blockIdx.y;
    int i = blockIdx.x * 256 + threadIdx.x;          // 0..131071
    if (y == 0) {
        long long b = (long long)i * 8;
        float4v o0, o1;
        if (bf) {
            short8 v = *(const short8*)((const bf16*)x_in + b);
            #pragma unroll
            for (int j = 0; j < 4; ++j) { o0[j] = bf2f(v[j]); o1[j] = bf2f(v[4 + j]); }
        } else {
            o0 = *(const float4v*)((const float*)x_in + b);
            o1 = *(const float4v*)((const float*)x_in + b + 4);
        }
        *(float4v*)(xbuf + b) = o0;
        *(float4v*)(xbuf + b + 4) = o1;
        // wave (64 lanes x 8 elems) == one row of 512: direct stats store
        float s = 0.f, q = 0.f;
        #pragma unroll
        for (int j = 0; j < 4; ++j) {
            s += o0[j] + o1[j];
            q += o0[j] * o0[j] + o1[j] * o1[j];
        }
        #pragma unroll
        for (int o = 32; o; o >>= 1) { s += __shfl_xor(s, o); q += __shfl_xor(q, o); }
        if ((threadIdx.x & 63) == 0) st0[i >> 6] = make_float2(s, q);
    } else {
        int s = y - 1;
        const void* src = (s == 0) ? r0 : ((s == 1) ? r1 : r2);
        int m = i >> 6, k8 = (i & 63) * 8;
        long long b = (long long)m * 512 + k8;
        short8 v;
        if (bf) {
            v = *(const short8*)((const bf16*)src + b);
        } else {
            float4v a0 = *(const float4v*)((const float*)src + b);
            float4v a1 = *(const float4v*)((const float*)src + b + 4);
            #pragma unroll
            for (int j = 0; j < 4; ++j) { v[j] = f2bf(a0[j]); v[4 + j] = f2bf(a1[j]); }
        }
        *(short8*)(rcat + (size_t)m * 1536 + s * 512 + k8) = v;
    }
}

// blocks [0,512): xbuf -> d_out x-region. blocks [512,8704): attn -> d_out.
__global__ __launch_bounds__(256) void outputs_kernel(
    const float* __restrict__ xbuf, const bf16* __restrict__ attn,
    void* __restrict__ out, const int* __restrict__ flagp) {
    bool bf = flagp[0] != 0;
    int bid = blockIdx.x;
    if (bid < 512) {
        long long b = ((long long)bid * 256 + threadIdx.x) * 8;
        float4v a0 = *(const float4v*)(xbuf + b);
        float4v a1 = *(const float4v*)(xbuf + b + 4);
        if (bf) {
            short8 v;
            #pragma unroll
            for (int j = 0; j < 4; ++j) { v[j] = f2bf(a0[j]); v[4 + j] = f2bf(a1[j]); }
            *(short8*)((bf16*)out + b) = v;
        } else {
            *(float4v*)((float*)out + b) = a0;
            *(float4v*)((float*)out + b + 4) = a1;
        }
    } else {
        long long e = ((long long)(bid - 512) * 256 + threadIdx.x) * 8;  // < 16777216
        short8 v = *(const short8*)(attn + e);
        if (bf) {
            *(short8*)((bf16*)out + 1048576 + e) = v;
        } else {
            float4v o0, o1;
            #pragma unroll
            for (int j = 0; j < 4; ++j) { o0[j] = bf2f(v[j]); o1[j] = bf2f(v[4 + j]); }
            float* op = (float*)out + 1048576 + e;
            *(float4v*)op = o0;
            *(float4v*)(op + 4) = o1;
        }
    }
}

// ---- all weight transposes (all 4 layers) in ONE exact-sized dispatch ----
// qkvT/ff1T rows scaled by gamma (fold); beta-dot partials atomicAdd'd into
// bBq/bBf from the staged (pre-gamma) tile.
__global__ __launch_bounds__(256) void prep_weights(
    const void* __restrict__ s0, const void* __restrict__ s1, const void* __restrict__ s2,
    const void* __restrict__ s3, const void* __restrict__ s4, const void* __restrict__ s5,
    const void* __restrict__ s6, const void* __restrict__ g1, const void* __restrict__ g2,
    const void* __restrict__ b1, const void* __restrict__ b2,
    float* __restrict__ bBq, float* __restrict__ bBf,
    bf16* __restrict__ arena, const int* __restrict__ flagp) {
    const bool bf = flagp[0] != 0;
    const int bid = blockIdx.x;
    const int l = bid / 960;
    const int rem = bid - l * 960;
    const int LW = 3932160;
    const int L = l * LW;

    int j, tile, tx, ldi, ldo;
    long long ioff;
    int dstoff;
    if (rem < 192)      { j = 0; tile = rem;                tx = 24; ldi = 1536; ldo = 512;
                          ioff = (long long)l * 786432;  dstoff = L; }
    else if (rem < 448) { j = 1 + ((rem - 192) >> 6); tile = (rem - 192) & 63; tx = 8; ldi = 512;
                          ioff = (long long)l * 262144;
                          if (j <= 3) { ldo = 1536; dstoff = L + 786432 + (j - 1) * 512; }
                          else        { ldo = 512;  dstoff = L + 1572864; } }
    else if (rem < 704) { j = 5; tile = rem - 448;          tx = 32; ldi = 2048; ldo = 512;
                          ioff = (long long)l * 1048576; dstoff = L + 1835008; }
    else                { j = 6; tile = rem - 704;          tx = 8;  ldi = 512;  ldo = 2048;
                          ioff = (long long)l * 1048576; dstoff = L + 2883584; }
    const void* in = (j == 0) ? s0 : (j == 1) ? s1 : (j == 2) ? s2 :
                     (j == 3) ? s3 : (j == 4) ? s4 : (j == 5) ? s5 : s6;
    const int gsel = (j == 0) ? 1 : ((j == 5) ? 2 : 0);
    bf16* out = arena + dstoff;
    const int bx = tile % tx, by = tile / tx;
    const int n0 = bx * 64, k0 = by * 64;
    const int tid = threadIdx.x;

    __shared__ bf16 t[64][72];
    __shared__ float red[4][64];

    if (bf) {
        const bf16* inb = (const bf16*)in + ioff;
        #pragma unroll
        for (int p = 0; p < 2; ++p) {
            int e = tid + p * 256;
            int r = e >> 3, c = (e & 7) * 8;
            *(uint4*)&t[r][c] = *(const uint4*)(inb + (size_t)(k0 + r) * ldi + n0 + c);
        }
    } else {
        const float* inf = (const float*)in + ioff;
        #pragma unroll
        for (int p = 0; p < 4; ++p) {
            int e = tid + p * 256;
            int r = e >> 4, c = (e & 15) * 4;
            float4v v = *(const float4v*)(inf + (size_t)(k0 + r) * ldi + n0 + c);
            union { bf16 h[4]; uint2v u; } w;
            #pragma unroll
            for (int q = 0; q < 4; ++q) w.h[q] = __float2bfloat16(v[q]);
            *reinterpret_cast<uint2v*>(&t[r][c]) = w.u;
        }
    }
    __syncthreads();
    #pragma unroll
    for (int p = 0; p < 2; ++p) {
        int e = tid + p * 256;
        int r = e >> 3, c = (e & 7) * 8;
        union { short8 s; uint4 u; } o;
        if (gsel) {
            const void* gp = (gsel == 1) ? g1 : g2;
            const long long go = (long long)l * 512 + k0 + c;
            #pragma unroll
            for (int q = 0; q < 8; ++q) {
                float gv = ldsel(gp, go + q, bf);
                o.s[q] = f2bf(bf2f(*reinterpret_cast<const short*>(&t[c + q][r])) * gv);
            }
        } else {
            #pragma unroll
            for (int q = 0; q < 8; ++q)
                o.s[q] = *reinterpret_cast<const short*>(&t[c + q][r]);
        }
        *(uint4*)(out + (size_t)(n0 + r) * ldo + k0 + c) = o.u;
    }

    // beta-dot partial: bB[n0+c] += sum_r beta[k0+r] * W[k0+r][n0+c]
    if (gsel) {
        const void* bp = (gsel == 1) ? b1 : b2;
        float* bout = (gsel == 1) ? (bBq + l * 1536 + n0) : (bBf + l * 2048 + n0);
        const int c = tid & 63, seg = tid >> 6;
        float partial = 0.f;
        #pragma unroll
        for (int q = 0; q < 16; ++q) {
            int r = seg * 16 + q;
            partial += ldsel(bp, (long long)l * 512 + k0 + r, bf)
                     * bf2f(*reinterpret_cast<const short*>(&t[r][c]));
        }
        red[seg][c] = partial;
        __syncthreads();
        if (seg == 0)
            atomicAdd(&bout[c], red[0][c] + red[1][c] + red[2][c] + red[3][c]);
    }
}

// ---- MFMA GEMM 64x64 tile (4 waves, 32x32 per wave), bf16 A ----
// EPI: 2 fp32 +bias+resid (+ row stats atomicAdd into stout); 5 bf16 store.
template<int EPI>
__global__ __launch_bounds__(256) void mgemm64(
    const bf16* __restrict__ A, int lda, long long sAb, long long sAh,
    const bf16* __restrict__ B, int ldb, long long sBb, long long sBh,
    void* __restrict__ Cv, int ldc, long long sCb, long long sCh,
    int K,
    const void* __restrict__ bias, long long biasoff,
    float* __restrict__ resid,
    float2* __restrict__ stout,
    const int* __restrict__ flagp) {
    const bool flg = flagp[0] != 0;
    const int tid = threadIdx.x;
    const int lane = tid & 63, wave = tid >> 6;
    const int m0 = blockIdx.y * 64, n0 = blockIdx.x * 64;
    const int zb = (int)(blockIdx.z >> 3), zh = (int)(blockIdx.z & 7);
    A += (size_t)zb * sAb + (size_t)zh * sAh;
    B += (size_t)zb * sBb + (size_t)zh * sBh;

    __shared__ bf16 As[64][40];
    __shared__ bf16 Bs[64][40];

    const int ar = tid >> 2, ak = (tid & 3) * 8;
    const bf16* Ap = A + (size_t)(m0 + ar) * lda + ak;
    const bf16* Bp = B + (size_t)(n0 + ar) * ldb + ak;

    const int wm = (wave >> 1) * 32, wn = (wave & 1) * 32;
    const int fr = lane & 15, fq = lane >> 4;

    float4v acc[2][2] = {};

    uint4 a0 = *(const uint4*)Ap;
    uint4 b0 = *(const uint4*)Bp;

    for (int k0 = 0; k0 < K; k0 += 32) {
        __syncthreads();
        *(uint4*)&As[ar][ak] = a0;
        *(uint4*)&Bs[ar][ak] = b0;
        if (k0 + 32 < K) {
            a0 = *(const uint4*)(Ap + k0 + 32);
            b0 = *(const uint4*)(Bp + k0 + 32);
        }
        __syncthreads();
        union { uint4 u; short8 s; } ua[2], ub[2];
        #pragma unroll
        for (int i = 0; i < 2; ++i) ua[i].u = *(const uint4*)&As[wm + i * 16 + fr][fq * 8];
        #pragma unroll
        for (int j = 0; j < 2; ++j) ub[j].u = *(const uint4*)&Bs[wn + j * 16 + fr][fq * 8];
        #pragma unroll
        for (int i = 0; i < 2; ++i)
            #pragma unroll
            for (int j = 0; j < 2; ++j)
                acc[i][j] = __builtin_amdgcn_mfma_f32_16x16x32_bf16(ua[i].s, ub[j].s, acc[i][j], 0, 0, 0);
    }

    if (EPI == 2) {
        float* C = (float*)Cv;
        #pragma unroll
        for (int i = 0; i < 2; ++i) {
            #pragma unroll
            for (int r = 0; r < 4; ++r) {
                int m = m0 + wm + i * 16 + fq * 4 + r;
                float s = 0.f, q = 0.f;
                #pragma unroll
                for (int j = 0; j < 2; ++j) {
                    int n = n0 + wn + j * 16 + fr;
                    float v = acc[i][j][r] + ldsel(bias, biasoff + n, flg)
                            + resid[(size_t)m * ldc + n];
                    C[(size_t)m * ldc + n] = v;
                    s += v; q += v * v;
                }
                #pragma unroll
                for (int o = 8; o; o >>= 1) { s += __shfl_xor(s, o); q += __shfl_xor(q, o); }
                if (fr == 0) {
                    atomicAdd(&stout[m].x, s);
                    atomicAdd(&stout[m].y, q);
                }
            }
        }
    } else {
        const long long coff = (long long)zb * sCb + (long long)zh * sCh;
        bf16* C = (bf16*)Cv + coff;
        #pragma unroll
        for (int i = 0; i < 2; ++i)
            #pragma unroll
            for (int j = 0; j < 2; ++j)
                #pragma unroll
                for (int r = 0; r < 4; ++r) {
                    int m = m0 + wm + i * 16 + fq * 4 + r;
                    int n = n0 + wn + j * 16 + fr;
                    C[(size_t)m * ldc + n] = __float2bfloat16(acc[i][j][r]);
                }
    }
}

// ---- LN-fused GEMM: fp32 A, raw row sums (st) -> mean/rstd inline in
// staging. B gamma-folded; bB beta-dot (+ extra bias). K=512, lda=512.
// EPI: 1 = qkv epilogue (qkvb + vT scatter), 3 = gelu bf16 store.
template<int EPI>
__global__ __launch_bounds__(256) void mgemm64f(
    const float* __restrict__ A, const float2* __restrict__ stats,
    const bf16* __restrict__ B, int ldb,
    void* __restrict__ Cv, int ldc,
    const float* __restrict__ bB,
    bf16* __restrict__ aux) {
    const int tid = threadIdx.x;
    const int lane = tid & 63, wave = tid >> 6;
    const int m0 = blockIdx.y * 64, n0 = blockIdx.x * 64;

    __shared__ bf16 As[64][40];
    __shared__ bf16 Bs[64][40];

    const int ar = tid >> 2, ak = (tid & 3) * 8;
    const float* Ap = A + (size_t)(m0 + ar) * 512 + ak;
    const bf16* Bp  = B + (size_t)(n0 + ar) * ldb + ak;
    const float2 sq = stats[m0 + ar];
    const float mean = sq.x * (1.f / 512.f);
    const float rstd = rsqrtf(sq.y * (1.f / 512.f) - mean * mean + 1e-5f);

    const int wm = (wave >> 1) * 32, wn = (wave & 1) * 32;
    const int fr = lane & 15, fq = lane >> 4;

    float4v acc[2][2] = {};

    float4v af0 = *(const float4v*)Ap;
    float4v af1 = *(const float4v*)(Ap + 4);
    uint4 b0 = *(const uint4*)Bp;

    for (int k0 = 0; k0 < 512; k0 += 32) {
        __syncthreads();
        union { bf16 h[8]; uint4 u; } w;
        #pragma unroll
        for (int u = 0; u < 4; ++u) {
            w.h[u]     = __float2bfloat16((af0[u] - mean) * rstd);
            w.h[4 + u] = __float2bfloat16((af1[u] - mean) * rstd);
        }
        *(uint4*)&As[ar][ak] = w.u;
        *(uint4*)&Bs[ar][ak] = b0;
        if (k0 + 32 < 512) {
            af0 = *(const float4v*)(Ap + k0 + 32);
            af1 = *(const float4v*)(Ap + k0 + 36);
            b0  = *(const uint4*)(Bp + k0 + 32);
        }
        __syncthreads();
        union { uint4 u; short8 s; } ua[2], ub[2];
        #pragma unroll
        for (int i = 0; i < 2; ++i) ua[i].u = *(const uint4*)&As[wm + i * 16 + fr][fq * 8];
        #pragma unroll
        for (int j = 0; j < 2; ++j) ub[j].u = *(const uint4*)&Bs[wn + j * 16 + fr][fq * 8];
        #pragma unroll
        for (int i = 0; i < 2; ++i)
            #pragma unroll
            for (int j = 0; j < 2; ++j)
                acc[i][j] = __builtin_amdgcn_mfma_f32_16x16x32_bf16(ua[i].s, ub[j].s, acc[i][j], 0, 0, 0);
    }

    #pragma unroll
    for (int i = 0; i < 2; ++i) {
        #pragma unroll
        for (int j = 0; j < 2; ++j) {
            #pragma unroll
            for (int r = 0; r < 4; ++r) {
                int m = m0 + wm + i * 16 + fq * 4 + r;
                int n = n0 + wn + j * 16 + fr;
                float v = acc[i][j][r] + bB[n];
                if (EPI == 1) {
                    bf16* C = (bf16*)Cv;
                    if (n < 1024) {
                        C[(size_t)m * ldc + n] = __float2bfloat16(v);
                    } else {
                        int h = (n >> 6) & 7, d = n & 63, ii = m & 1023, bb = m >> 10;
                        aux[(size_t)(bb * 8 + h) * 65536 + (size_t)d * 1024 + ii] = __float2bfloat16(v);
                    }
                } else if (EPI == 3) {
                    bf16* C = (bf16*)Cv;
                    C[(size_t)m * ldc + n] = __float2bfloat16(0.5f * v * (1.f + erff(v * 0.70710678118f)));
                }
            }
        }
    }
}

// ---- BD producer: P = (q . wsum)/3 for all 8 heads, rel-shift scatter into
// interleaved Scb[(t-1024)*8 + h]. Register-prefetch across the h-loop.
__global__ __launch_bounds__(512) void bd_kernel(
    const bf16* __restrict__ qkvb, const bf16* __restrict__ wsum,
    bf16* __restrict__ Scb) {
    const int tid = threadIdx.x;
    const int lane = tid & 63, wave = tid >> 6;
    const int n0 = blockIdx.x * 64, m0 = blockIdx.y * 64, b = blockIdx.z;

    __shared__ bf16 Qs[64][72];
    __shared__ bf16 Ws[64][72];

    const int r0 = tid >> 3, c0 = (tid & 7) * 8;
    const bf16* Qp = qkvb + (size_t)(b * 1024 + m0 + r0) * 1536 + c0;
    const bf16* Wp = wsum + (size_t)(b * 1024 + n0 + r0) * 512 + c0;

    const int wm = (wave >> 2) * 32, wn = (wave & 3) * 16;
    const int fr = lane & 15, fq = lane >> 4;

    float4v acc[8][2] = {};

    uint4 qreg = *(const uint4*)Qp;
    uint4 wreg = *(const uint4*)Wp;

    for (int h = 0; h < 8; ++h) {
        __syncthreads();
        *(uint4*)&Qs[r0][c0] = qreg;
        *(uint4*)&Ws[r0][c0] = wreg;
        if (h < 7) {
            qreg = *(const uint4*)(Qp + (h + 1) * 64);
            wreg = *(const uint4*)(Wp + (h + 1) * 64);
        }
        __syncthreads();
        #pragma unroll
        for (int ks = 0; ks < 2; ++ks) {
            union { uint4 u; short8 s; } ua[2], ub;
            #pragma unroll
            for (int i = 0; i < 2; ++i) ua[i].u = *(const uint4*)&Qs[wm + i * 16 + fr][fq * 8 + ks * 32];
            ub.u = *(const uint4*)&Ws[wn + fr][fq * 8 + ks * 32];
            #pragma unroll
            for (int i = 0; i < 2; ++i)
                acc[h][i] = __builtin_amdgcn_mfma_f32_16x16x32_bf16(ua[i].s, ub.s, acc[h][i], 0, 0, 0);
        }
    }

    const size_t pb = (size_t)b * 8388608;
    #pragma unroll
    for (int i = 0; i < 2; ++i) {
        #pragma unroll
        for (int r = 0; r < 4; ++r) {
            int m = m0 + wm + i * 16 + fq * 4 + r;
            int n = n0 + wn + fr;
            int t = m * 1025 + n + 1;
            if (t >= 1024) {
                short8 v;
                #pragma unroll
                for (int h = 0; h < 8; ++h) v[h] = f2bf(acc[h][i][r] * (1.f / 3.f));
                *(short8*)(Scb + pb + (size_t)(t - 1024) * 8) = v;
            }
        }
    }
}

// ---- fused AC + BD + softmax-over-h. 8 waves, 64x64 (i,j) tile. ----
__global__ __launch_bounds__(512) void scores_kernel(
    const bf16* __restrict__ qkvb, const bf16* __restrict__ Scb,
    bf16* __restrict__ attn) {
    const int tid = threadIdx.x;
    const int lane = tid & 63, wave = tid >> 6;
    const int j0 = blockIdx.x * 64, i0 = blockIdx.y * 64, b = blockIdx.z;

    __shared__ bf16 Qs[64][72];
    __shared__ bf16 Ks[64][72];

    const int r0 = tid >> 3, c0 = (tid & 7) * 8;
    const bf16* Qp = qkvb + (size_t)(b * 1024 + i0 + r0) * 1536 + c0;
    const bf16* Kp = qkvb + (size_t)(b * 1024 + j0 + r0) * 1536 + 512 + c0;

    const int wm = (wave >> 2) * 32, wn = (wave & 3) * 16;
    const int fr = lane & 15, fq = lane >> 4;

    float4v acc[8][2] = {};

    uint4 qreg = *(const uint4*)Qp;
    uint4 kreg = *(const uint4*)Kp;

    for (int h = 0; h < 8; ++h) {
        __syncthreads();
        *(uint4*)&Qs[r0][c0] = qreg;
        *(uint4*)&Ks[r0][c0] = kreg;
        if (h < 7) {
            qreg = *(const uint4*)(Qp + (h + 1) * 64);
            kreg = *(const uint4*)(Kp + (h + 1) * 64);
        }
        __syncthreads();
        #pragma unroll
        for (int ks = 0; ks < 2; ++ks) {
            union { uint4 u; short8 s; } ua[2], ub;
            #pragma unroll
            for (int i = 0; i < 2; ++i) ua[i].u = *(const uint4*)&Qs[wm + i * 16 + fr][fq * 8 + ks * 32];
            ub.u = *(const uint4*)&Ks[wn + fr][fq * 8 + ks * 32];
            #pragma unroll
            for (int i = 0; i < 2; ++i)
                acc[h][i] = __builtin_amdgcn_mfma_f32_16x16x32_bf16(ua[i].s, ub.s, acc[h][i], 0, 0, 0);
        }
    }

    // pass 1: per-element max + inv-sum over h (bd kept in registers)
    short8 bdv[8];
    float mxs[8], invs[8];
    const size_t pb = (size_t)b * 8388608;
    #pragma unroll
    for (int i = 0; i < 2; ++i) {
        #pragma unroll
        for (int r = 0; r < 4; ++r) {
            const int e = i * 4 + r;
            int gi = i0 + wm + i * 16 + fq * 4 + r;
            int gj = j0 + wn + fr;
            bdv[e] = *(const short8*)(Scb + pb + ((size_t)gi * 1024 + gj) * 8);
            bool diag = (gj == gi + 1);
            float dv[8];
            float mx = -3.4e38f;
            #pragma unroll
            for (int h = 0; h < 8; ++h) {
                float bd = diag ? 0.f : bf2f(bdv[e][h]);
                dv[h] = (acc[h][i][r] + bd) * 0.125f;
                mx = fmaxf(mx, dv[h]);
            }
            float s = 0.f;
            #pragma unroll
            for (int h = 0; h < 8; ++h) s += __expf(dv[h] - mx);
            mxs[e] = mx; invs[e] = 1.f / s;
        }
    }

    // pass 2: per h, stage 64x64 bf16 tile in LDS (Qs reused), write full rows.
    const size_t ab = (size_t)b * 8388608;
    const int orow = tid >> 3, ocol = (tid & 7) * 8;
    #pragma unroll
    for (int h = 0; h < 8; ++h) {
        __syncthreads();
        #pragma unroll
        for (int i = 0; i < 2; ++i) {
            #pragma unroll
            for (int r = 0; r < 4; ++r) {
                const int e = i * 4 + r;
                int gil = wm + i * 16 + fq * 4 + r;
                int gjl = wn + fr;
                int gi = i0 + gil, gj = j0 + gjl;
                float bd = (gj == gi + 1) ? 0.f : bf2f(bdv[e][h]);
                float a = __expf((acc[h][i][r] + bd) * 0.125f - mxs[e]) * invs[e];
                Qs[gil][gjl] = __float2bfloat16(a);
            }
        }
        __syncthreads();
        *(uint4*)(attn + ab + (size_t)h * 1048576 + (size_t)(i0 + orow) * 1024 + j0 + ocol)
            = *(const uint4*)&Qs[orow][ocol];
    }
}

extern "C" void kernel_launch(void* const* d_in, const int* in_sizes, int n_in,
                              void* d_out, int out_size, void* d_ws, size_t ws_size,
                              hipStream_t stream) {
    (void)in_sizes; (void)n_in; (void)out_size; (void)ws_size;
    const void* x_in    = d_in[0];
    const void* r_t     = d_in[1];
    const void* r_c     = d_in[2];
    const void* r_p     = d_in[3];
    const void* bias_pf = d_in[4];
    const void* ln1_g   = d_in[5];
    const void* ln1_b   = d_in[6];
    const void* w_qkv   = d_in[7];
    const void* w_outw  = d_in[8];
    const void* b_out   = d_in[9];
    const void* w_kt    = d_in[10];
    const void* w_kc    = d_in[11];
    const void* w_kp    = d_in[12];
    const void* ln2_g   = d_in[13];
    const void* ln2_b   = d_in[14];
    const void* w_ff1   = d_in[15];
    const void* b_ff1   = d_in[16];
    const void* w_ff2   = d_in[17];
    const void* b_ff2   = d_in[18];

    float* xbuf  = (float*)d_ws;                 // 1M fp32
    bf16* base16 = (bf16*)(xbuf + 1048576);
    bf16* Scb   = base16;                        // 16M (h1 aliases first 4M)
    bf16* h1    = base16;
    bf16* attn  = base16 + 16777216;             // 16M
    bf16* xnb   = attn + 16777216;               // 1M
    bf16* qkvb  = xnb + 1048576;                 // 3M
    bf16* vT    = qkvb + 3145728;                // 1M
    bf16* wsum4 = vT + 1048576;                  // 4M (all 4 layers)
    bf16* rcat  = wsum4 + 4194304;               // 3M
    bf16* arena = rcat + 3145728;                // 15.75M
    int*   flagp = (int*)(arena + 15728640);
    float* bBq4  = (float*)(flagp + 16);         // 4*1536
    float* bBf4  = bBq4 + 6144;                  // 4*2048
    float2* st8  = (float2*)(bBf4 + 8192);       // 9*2048 float2
    // stage s of st8: 2l = LN1 sums of layer l; 2l+1 = LN2 sums; 8 = scratch

    const int LW = 3932160;
    const int WCAT_O = 786432, OUT_O = 1572864, FF1_O = 1835008, FF2_O = 2883584;
    const int QKV_O = 0;

    dim3 blk(256), blk8(512);

    detect_kernel<<<1, 64, 0, stream>>>((const unsigned int*)ln1_g, flagp);
    init_kernel<<<200, blk, 0, stream>>>(bias_pf, b_ff1, bBq4, bBf4, (float*)st8, flagp);
    input_prep<<<dim3(512, 4), blk, 0, stream>>>(x_in, r_t, r_c, r_p, xbuf, rcat, st8, flagp);

    prep_weights<<<3840, blk, 0, stream>>>(
        w_qkv, w_kt, w_kc, w_kp, w_outw, w_ff1, w_ff2, ln1_g, ln2_g,
        ln1_b, ln2_b, bBq4, bBf4, arena, flagp);

    // wsum for ALL layers, batched (z = layer): wsum4[l] = rcat @ wcatT[l]^T
    mgemm64<5><<<dim3(8, 32, 4), blk, 0, stream>>>(
        rcat, 1536, 0, 0, arena + WCAT_O, 1536, 0, LW,
        wsum4, 512, 0, 1048576, 1536, nullptr, 0, nullptr, nullptr, flagp);

    for (int l = 0; l < 4; ++l) {
        const bf16* qkvT  = arena + l * LW + QKV_O;
        const bf16* outT  = arena + l * LW + OUT_O;
        const bf16* ff1T  = arena + l * LW + FF1_O;
        const bf16* ff2T  = arena + l * LW + FF2_O;
        const bf16* wsum  = wsum4 + (size_t)l * 1048576;

        // qkv = LN1(x) @ (g1.qkvT)^T + bBq (stats from st8[2l]); v -> vT
        mgemm64f<1><<<dim3(24, 32), blk, 0, stream>>>(
            xbuf, st8 + (size_t)(2 * l) * 2048, qkvT, 512, qkvb, 1536,
            bBq4 + l * 1536, vT);
        // Scb[(t-1024)*8+h] = rel_shift(q . wsum)/3, packed over h
        bd_kernel<<<dim3(16, 16, 2), blk8, 0, stream>>>(qkvb, wsum, Scb);
        // fused AC + BD + softmax -> attn
        scores_kernel<<<dim3(16, 16, 2), blk8, 0, stream>>>(qkvb, Scb, attn);
        // out = attn @ vT^T -> xnb
        mgemm64<5><<<dim3(1, 16, 16), blk, 0, stream>>>(
            attn, 1024, 8388608, 1048576, vT, 1024, 524288, 65536,
            xnb, 512, 524288, 64, 1024, nullptr, 0, nullptr, nullptr, flagp);
        // x = out @ outT^T + b_out + x (fp32) + LN2 row sums -> st8[2l+1]
        mgemm64<2><<<dim3(8, 32, 1), blk, 0, stream>>>(
            xnb, 512, 0, 0, outT, 512, 0, 0,
            xbuf, 512, 0, 0, 512, b_out, (long long)l * 512, xbuf,
            st8 + (size_t)(2 * l + 1) * 2048, flagp);
        // h1 = gelu(LN2(x) @ (g2.ff1T)^T + bBf) (stats from st8[2l+1])
        mgemm64f<3><<<dim3(32, 32), blk, 0, stream>>>(
            xbuf, st8 + (size_t)(2 * l + 1) * 2048, ff1T, 512, h1, 2048,
            bBf4 + l * 2048, nullptr);
        // x = h1 @ ff2T^T + b_ff2 + x (fp32) + next LN1 sums -> st8[2l+2]
        mgemm64<2><<<dim3(8, 32, 1), blk, 0, stream>>>(
            h1, 2048, 0, 0, ff2T, 2048, 0, 0,
            xbuf, 512, 0, 0, 2048, b_ff2, (long long)l * 512, xbuf,
            st8 + (size_t)(2 * l + 2) * 2048, flagp);
    }

    // x -> d_out[0..1M), attn -> d_out[1M..17M), one dispatch
    outputs_kernel<<<8704, blk, 0, stream>>>(xbuf, attn, d_out, flagp);
}